// Round 2
// baseline (1024.290 us; speedup 1.0000x reference)
//
#include <hip/hip_runtime.h>
#include <hip/hip_bf16.h>
#include <math.h>

using bf16 = __hip_bfloat16;

#define DEV static __device__ __forceinline__

constexpr int NENT = 40000;
constexpr int DIM  = 200;
constexpr int EE   = 80000;      // edges per side
constexpr int TOTE = 2 * EE;     // 160000
constexpr int BQ   = 1024;
constexpr float EPSBN = 1e-5f;
constexpr size_t XOFF = (size_t)2 * BQ * DIM;   // x-region element offset inside d_out

// MFMA geometry: N padded to 208 (13x16), K padded to 224 (7x32)
constexpr int KP   = 224;
constexpr int NP   = 208;
constexpr int LDAS = 232;        // LDS A stride (ushorts): 464B rows -> 2-way-max bank aliasing
constexpr int MT_LOOP = (NENT + 127) / 128;  // 313 (loop kernel M=128)
constexpr int MT_SIDE = EE / 64;             // 1250 (per-side edge kernel M=64)

typedef __attribute__((ext_vector_type(8))) short s8v;   // 8 x bf16 (4 VGPRs)
typedef __attribute__((ext_vector_type(4))) float f4v;   // MFMA accumulator

struct MP { const void* p; };    // world-dtype (bf16|f32) pointer, runtime flag

DEV float b2f(unsigned int u) { union { unsigned int i; float f; } v; v.i = u << 16; return v.f; }

DEV float ld(MP m, size_t i, int bf) {
  return bf ? b2f(((const unsigned short*)m.p)[i]) : ((const float*)m.p)[i];
}
DEV void ld8(MP m, size_t i, float* o, int bf) {
  if (bf) {
    uint4 u = *(const uint4*)((const unsigned short*)m.p + i);
    o[0]=b2f(u.x & 0xffffu); o[1]=b2f(u.x >> 16);
    o[2]=b2f(u.y & 0xffffu); o[3]=b2f(u.y >> 16);
    o[4]=b2f(u.z & 0xffffu); o[5]=b2f(u.z >> 16);
    o[6]=b2f(u.w & 0xffffu); o[7]=b2f(u.w >> 16);
  } else {
    const float4* q = (const float4*)((const float*)m.p + i);
    float4 a = q[0], b = q[1];
    o[0]=a.x; o[1]=a.y; o[2]=a.z; o[3]=a.w; o[4]=b.x; o[5]=b.y; o[6]=b.z; o[7]=b.w;
  }
}
DEV void f32load8(const float* p, float* o) {
  const float4* q = (const float4*)p;
  float4 a = q[0], b = q[1];
  o[0]=a.x; o[1]=a.y; o[2]=a.z; o[3]=a.w; o[4]=b.x; o[5]=b.y; o[6]=b.z; o[7]=b.w;
}
DEV void st(void* p, size_t i, float v, int bf) {
  if (bf) ((bf16*)p)[i] = __float2bfloat16(v);
  else    ((float*)p)[i] = v;
}
DEV unsigned short f2b(float f) {   // RNE f32 -> bf16 bits (inputs never NaN)
  union { float f; unsigned int i; } v; v.f = f;
  return (unsigned short)((v.i + 0x7fffu + ((v.i >> 16) & 1u)) >> 16);
}
DEV uint4 pack8(const float* o) {
  uint4 u;
  u.x = (unsigned)f2b(o[0]) | ((unsigned)f2b(o[1]) << 16);
  u.y = (unsigned)f2b(o[2]) | ((unsigned)f2b(o[3]) << 16);
  u.z = (unsigned)f2b(o[4]) | ((unsigned)f2b(o[5]) << 16);
  u.w = (unsigned)f2b(o[6]) | ((unsigned)f2b(o[7]) << 16);
  return u;
}

// ---------------- dtype detect ----------------
__global__ void detect_kernel(const unsigned short* __restrict__ e, int* __restrict__ flag) {
  int tid = threadIdx.x;
  int absurd = 0;
  for (int i = tid; i < 2048; i += 64) {
    int ex = (e[i] >> 7) & 0xFF;
    if (ex >= 0xD0 || (ex != 0 && ex <= 0x50)) absurd++;
  }
  for (int o = 32; o; o >>= 1) absurd += __shfl_down(absurd, o);
  if (tid == 0) *flag = (absurd > 64) ? 0 : 1;   // 1 => bf16 world
}

// ---------------- small kernels ----------------
__global__ void deg_hist_kernel(const int* __restrict__ ei,
                                float* __restrict__ deg_in, float* __restrict__ deg_out) {
  int i = blockIdx.x * 256 + threadIdx.x;
  if (i >= TOTE) return;
  atomicAdd((i < EE ? deg_in : deg_out) + ei[i], 1.0f);
}

__global__ void norm_kernel(const int* __restrict__ ei,
                            const float* __restrict__ deg_in, const float* __restrict__ deg_out,
                            float* __restrict__ normA) {
  int i = blockIdx.x * 256 + threadIdx.x;
  if (i >= TOTE) return;
  int s = ei[i], d = ei[TOTE + i];
  const float* deg = (i < EE) ? deg_in : deg_out;
  float a = deg[s], b = deg[d];
  float na = a > 0.f ? rsqrtf(a) : 0.f;
  float nb = b > 0.f ? rsqrtf(b) : 0.f;
  normA[i] = na * nb;
}

// ---------------- dst-sort (counting sort per side) ----------------
__global__ void cnt_kernel(const int* __restrict__ ei, int* __restrict__ cnt) {
  int i = blockIdx.x * 256 + threadIdx.x;
  if (i >= TOTE) return;
  int side = (i >= EE) ? 1 : 0;
  atomicAdd(cnt + side * NENT + ei[TOTE + i], 1);
}

// 2 blocks (one per side), 256 threads: exclusive scan of cnt -> offs (+copy to tmpo)
__global__ __launch_bounds__(256) void scan_kernel(const int* __restrict__ cnt,
                                                   int* __restrict__ offs,
                                                   int* __restrict__ tmpo) {
  __shared__ int part[256];
  const int side = blockIdx.x;
  const int* c = cnt + side * NENT;
  int* o  = offs + side * (NENT + 1);
  int* tp = tmpo + side * NENT;
  const int t = threadIdx.x;
  const int CH = (NENT + 255) / 256;           // 157
  int lo = t * CH; if (lo > NENT) lo = NENT;
  int hi = lo + CH; if (hi > NENT) hi = NENT;
  int s = 0;
  for (int i = lo; i < hi; ++i) s += c[i];
  part[t] = s;
  __syncthreads();
  for (int d = 1; d < 256; d <<= 1) {
    int v = (t >= d) ? part[t - d] : 0;
    __syncthreads();
    part[t] += v;
    __syncthreads();
  }
  int run = (t == 0) ? 0 : part[t - 1];
  for (int i = lo; i < hi; ++i) { o[i] = run; tp[i] = run; run += c[i]; }
  if (t == 255) o[NENT] = run;                 // == EE
}

__global__ void scatter_kernel(const int* __restrict__ ei, int* __restrict__ tmpo,
                               int* __restrict__ perm) {
  int i = blockIdx.x * 256 + threadIdx.x;
  if (i >= TOTE) return;
  int side = (i >= EE) ? 1 : 0;
  int d = ei[TOTE + i];
  int p = atomicAdd(tmpo + side * NENT + d, 1);
  perm[side * EE + p] = i;
}

__global__ void copy_f32_kernel(MP s, float* __restrict__ d, int n, const int* __restrict__ flagp) {
  int bf = *flagp;
  int i = blockIdx.x * 256 + threadIdx.x;
  if (i < n) d[i] = ld(s, i, bf);
}

__global__ void mat200_kernel(MP A, int a_use_flag, MP B, float* __restrict__ C,
                              const int* __restrict__ flagp) {
  int bf = *flagp;
  int abf = a_use_flag ? bf : 0;
  int i = blockIdx.x, c = threadIdx.x;
  if (c >= DIM) return;
  float acc = 0.f;
  for (int d = 0; d < DIM; ++d)
    acc = fmaf(ld(A, (size_t)i * DIM + d, abf), ld(B, (size_t)d * DIM + c, bf), acc);
  C[(size_t)i * DIM + c] = acc;
}

// Bt[n][k] = W^T padded to [208][224] bf16, optionally folding loop_rel
__global__ void btprep_kernel(MP w, MP lrp, int has_lr, unsigned short* __restrict__ bt,
                              const int* __restrict__ flagp) {
  int bf = *flagp;
  int n = blockIdx.x, k = threadIdx.x;
  if (k >= KP) return;
  float v = 0.f;
  if (n < DIM && k < DIM) {
    v = ld(w, (size_t)k * DIM + n, bf);
    if (has_lr) v *= ld(lrp, k, bf);
  }
  bt[(size_t)n * KP + k] = f2b(v);
}

// ---------------- loop (self-edge) MFMA GEMM: agg = x @ wp'  (M=128, plain store) ----------------
__global__ __launch_bounds__(256, 2) void loop_mfma(
    MP x, size_t xoff, const unsigned short* __restrict__ Bt,
    float* __restrict__ agg, const int* __restrict__ flagp) {
  __shared__ unsigned short As[128][LDAS];
  const int bf  = *flagp;
  const int tid = threadIdx.x;
  const int m0  = blockIdx.x * 128;

#pragma unroll
  for (int it = 0; it < 14; ++it) {
    int i = tid + it * 256;
    int r = i / 28, cg = i - r * 28;
    float o[8] = {0,0,0,0,0,0,0,0};
    int row = m0 + r;
    if (row < NENT && cg < 25) ld8(x, xoff + (size_t)row * DIM + cg * 8, o, bf);
    *(uint4*)&As[r][cg * 8] = pack8(o);
  }
  __syncthreads();

  const int lane = tid & 63;
  const int w    = tid >> 6;
  const int col  = lane & 15;
  const int quad = lane >> 4;
  const unsigned short* btl = Bt + (size_t)col * KP + quad * 8;

  f4v acc[26];
#pragma unroll
  for (int t = 0; t < 26; ++t) acc[t] = (f4v){0.f, 0.f, 0.f, 0.f};

  const int rbase = w * 32;
#pragma unroll
  for (int kc = 0; kc < 7; ++kc) {
    const int k0 = kc * 32;
    s8v a0 = __builtin_bit_cast(s8v, *(const uint4*)&As[rbase + col][k0 + quad * 8]);
    s8v a1 = __builtin_bit_cast(s8v, *(const uint4*)&As[rbase + 16 + col][k0 + quad * 8]);
#pragma unroll
    for (int nt = 0; nt < 13; ++nt) {
      s8v b = __builtin_bit_cast(s8v, *(const uint4*)(btl + (size_t)nt * 16 * KP + k0));
      acc[nt]      = __builtin_amdgcn_mfma_f32_16x16x32_bf16(a0, b, acc[nt], 0, 0, 0);
      acc[13 + nt] = __builtin_amdgcn_mfma_f32_16x16x32_bf16(a1, b, acc[13 + nt], 0, 0, 0);
    }
  }

#pragma unroll
  for (int mt = 0; mt < 2; ++mt) {
#pragma unroll
    for (int i = 0; i < 4; ++i) {
      const int grow = m0 + rbase + mt * 16 + quad * 4 + i;
      if (grow < NENT) {
        float* ap = agg + (size_t)grow * DIM;
#pragma unroll
        for (int nt = 0; nt < 13; ++nt) {
          int n = nt * 16 + col;
          if (n < DIM) ap[n] = acc[mt * 13 + nt][i];
        }
      }
    }
  }
}

// ---------------- phase A: qual GEMM -> rel_e -> m (LDS C->A) -> msg GEMM -> coalesced store ----
// Two-pass N-split per wave: each GEMM is computed in halves (nt 0..6, then 7..12) with a
// 7-wide accumulator, cutting unified VGPR+AGPR pressure from ~104 to ~95 -> 5 blocks/CU.
// ep1a buffers its m-half in registers (As still holds the t1 A-fragments that GEMM1b reads);
// ep1b flushes both halves to the wave-private As rows.  No barrier changes: each wave still
// touches only As rows [16w, 16w+16) after staging.
__global__ __launch_bounds__(256, 5) void edge_msg(
    MP x, size_t xoff, const float* __restrict__ re,
    const int* __restrict__ ei, const int* __restrict__ ety,
    const int* __restrict__ qe, const int* __restrict__ qr,
    const float* __restrict__ normA, const int* __restrict__ permS,
    const unsigned short* __restrict__ BtQ, const unsigned short* __restrict__ BtW,
    float* __restrict__ msg, const int* __restrict__ flagp) {
  __shared__ unsigned short As[64][LDAS];           // 29.7 KB
  __shared__ int sQe0[64], sQe1[64], sQr0[64], sQr1[64], sSrc[64], sEty[64];
  __shared__ float sN[64];

  const int bf  = *flagp;
  const int tid = threadIdx.x;
  const int m0  = blockIdx.x * 64;                  // position within this side's sorted order

  if (tid < 64) {
    int e = permS[m0 + tid];                        // original edge id
    sQe0[tid] = qe[e];        sQe1[tid] = qe[TOTE + e];
    sQr0[tid] = qr[e];        sQr1[tid] = qr[TOTE + e];
    sSrc[tid] = ei[e];        sEty[tid] = ety[e];
    sN[tid]   = normA[e];
  }
  __syncthreads();

  // stage t1 = sum_q x[qe]*re[qr] into As (64 x 224 bf16), pad cols zeroed
#pragma unroll
  for (int it = 0; it < 7; ++it) {
    int i = tid + it * 256;
    int r = i / 28, cg = i - r * 28;
    float o[8] = {0,0,0,0,0,0,0,0};
    if (cg < 25) {
      float xa[8], ra[8], xb[8], rb[8];
      ld8(x, xoff + (size_t)sQe0[r] * DIM + cg * 8, xa, bf);
      f32load8(re + (size_t)sQr0[r] * DIM + cg * 8, ra);
      ld8(x, xoff + (size_t)sQe1[r] * DIM + cg * 8, xb, bf);
      f32load8(re + (size_t)sQr1[r] * DIM + cg * 8, rb);
#pragma unroll
      for (int j = 0; j < 8; ++j) o[j] = xa[j] * ra[j] + xb[j] * rb[j];
    }
    *(uint4*)&As[r][cg * 8] = pack8(o);
  }
  __syncthreads();
  // ---- from here on, wave w touches only As rows [16w, 16w+16) ----

  const int lane = tid & 63;
  const int w    = tid >> 6;
  const int col  = lane & 15;
  const int quad = lane >> 4;
  const int rbase = w * 16;
  const unsigned short* btlQ = BtQ + (size_t)col * KP + quad * 8;
  const unsigned short* btlW = BtW + (size_t)col * KP + quad * 8;

  f4v acc[7];
  float mA[4][7];                                   // buffered m cols 0..111

  // GEMM 1a: qual cols 0..111 (nt 0..6)
#pragma unroll
  for (int t = 0; t < 7; ++t) acc[t] = (f4v){0.f, 0.f, 0.f, 0.f};
#pragma unroll
  for (int kc = 0; kc < 7; ++kc) {
    const int k0 = kc * 32;
    s8v a = __builtin_bit_cast(s8v, *(const uint4*)&As[rbase + col][k0 + quad * 8]);
#pragma unroll
    for (int nt = 0; nt < 7; ++nt) {
      s8v b = __builtin_bit_cast(s8v, *(const uint4*)(btlQ + (size_t)nt * 16 * KP + k0));
      acc[nt] = __builtin_amdgcn_mfma_f32_16x16x32_bf16(a, b, acc[nt], 0, 0, 0);
    }
  }
  // ep1a: m cols 0..111 -> registers (As must stay intact for GEMM 1b)
#pragma unroll
  for (int i = 0; i < 4; ++i) {
    const int lrow = rbase + quad * 4 + i;
    const float* rerow = re + (size_t)sEty[lrow] * DIM;
    const size_t xrow = xoff + (size_t)sSrc[lrow] * DIM;
#pragma unroll
    for (int nt = 0; nt < 7; ++nt) {
      const int n = nt * 16 + col;                  // <= 111 < DIM, no guard needed
      mA[i][nt] = ld(x, xrow + n, bf) * (0.5f * (rerow[n] + acc[nt][i]));
    }
  }

  // GEMM 1b: qual cols 112..207 (nt 7..12)
#pragma unroll
  for (int t = 0; t < 6; ++t) acc[t] = (f4v){0.f, 0.f, 0.f, 0.f};
#pragma unroll
  for (int kc = 0; kc < 7; ++kc) {
    const int k0 = kc * 32;
    s8v a = __builtin_bit_cast(s8v, *(const uint4*)&As[rbase + col][k0 + quad * 8]);
#pragma unroll
    for (int nt = 0; nt < 6; ++nt) {
      s8v b = __builtin_bit_cast(s8v, *(const uint4*)(btlQ + (size_t)(nt + 7) * 16 * KP + k0));
      acc[nt] = __builtin_amdgcn_mfma_f32_16x16x32_bf16(a, b, acc[nt], 0, 0, 0);
    }
  }
  // ep1b: finish m (cols 112..199), flush mA, zero k-pads -> own As rows
#pragma unroll
  for (int i = 0; i < 4; ++i) {
    const int lrow = rbase + quad * 4 + i;
    const float* rerow = re + (size_t)sEty[lrow] * DIM;
    const size_t xrow = xoff + (size_t)sSrc[lrow] * DIM;
#pragma unroll
    for (int nt = 0; nt < 6; ++nt) {
      const int n = (nt + 7) * 16 + col;            // 112..207
      float v = 0.f;
      if (n < DIM) v = ld(x, xrow + n, bf) * (0.5f * (rerow[n] + acc[nt][i]));
      As[lrow][n] = f2b(v);
    }
#pragma unroll
    for (int nt = 0; nt < 7; ++nt) As[lrow][nt * 16 + col] = f2b(mA[i][nt]);
    As[lrow][NP + col] = 0;                         // zero k-pad cols 208..223
  }

  // GEMM 2a: msg cols 0..111 (same wave-private As rows; lgkmcnt orders write->read)
#pragma unroll
  for (int t = 0; t < 7; ++t) acc[t] = (f4v){0.f, 0.f, 0.f, 0.f};
#pragma unroll
  for (int kc = 0; kc < 7; ++kc) {
    const int k0 = kc * 32;
    s8v a = __builtin_bit_cast(s8v, *(const uint4*)&As[rbase + col][k0 + quad * 8]);
#pragma unroll
    for (int nt = 0; nt < 7; ++nt) {
      s8v b = __builtin_bit_cast(s8v, *(const uint4*)(btlW + (size_t)nt * 16 * KP + k0));
      acc[nt] = __builtin_amdgcn_mfma_f32_16x16x32_bf16(a, b, acc[nt], 0, 0, 0);
    }
  }
#pragma unroll
  for (int i = 0; i < 4; ++i) {
    const int lrow = rbase + quad * 4 + i;
    const float nv = sN[lrow];
    float* mp = msg + (size_t)(m0 + lrow) * DIM;
#pragma unroll
    for (int nt = 0; nt < 7; ++nt) mp[nt * 16 + col] = acc[nt][i] * nv;   // n <= 111
  }

  // GEMM 2b: msg cols 112..199
#pragma unroll
  for (int t = 0; t < 6; ++t) acc[t] = (f4v){0.f, 0.f, 0.f, 0.f};
#pragma unroll
  for (int kc = 0; kc < 7; ++kc) {
    const int k0 = kc * 32;
    s8v a = __builtin_bit_cast(s8v, *(const uint4*)&As[rbase + col][k0 + quad * 8]);
#pragma unroll
    for (int nt = 0; nt < 6; ++nt) {
      s8v b = __builtin_bit_cast(s8v, *(const uint4*)(btlW + (size_t)(nt + 7) * 16 * KP + k0));
      acc[nt] = __builtin_amdgcn_mfma_f32_16x16x32_bf16(a, b, acc[nt], 0, 0, 0);
    }
  }
#pragma unroll
  for (int i = 0; i < 4; ++i) {
    const int lrow = rbase + quad * 4 + i;
    const float nv = sN[lrow];
    float* mp = msg + (size_t)(m0 + lrow) * DIM;
#pragma unroll
    for (int nt = 0; nt < 6; ++nt) {
      const int n = (nt + 7) * 16 + col;
      if (n < DIM) mp[n] = acc[nt][i] * nv;
    }
  }
}

// ---------------- phase B: contiguous segmented sum  agg[d] += sum(msg[offs[d]:offs[d+1]]) ----
// msg rows for entity d are contiguous (dst-sorted) -> fully streaming float4 reads.
__global__ __launch_bounds__(256) void segsum_kernel(const float4* __restrict__ msg4,
                                                     const int* __restrict__ offs,
                                                     float4* __restrict__ agg4) {
  const int lane = threadIdx.x & 63;
  const int w    = threadIdx.x >> 6;
  if (lane >= 50) return;                 // 50 float4 = 200 cols
  const int rbase = blockIdx.x * 16 + w * 4;
#pragma unroll
  for (int rr = 0; rr < 4; ++rr) {
    const int d = rbase + rr;
    const size_t ap = (size_t)d * 50 + lane;
    float4 v = agg4[ap];
    int b = offs[d], e = offs[d + 1];
    int k = b;
    for (; k + 1 < e; k += 2) {
      float4 m1 = msg4[(size_t)k * 50 + lane];
      float4 m2 = msg4[(size_t)(k + 1) * 50 + lane];
      v.x += m1.x + m2.x; v.y += m1.y + m2.y; v.z += m1.z + m2.z; v.w += m1.w + m2.w;
    }
    if (k < e) {
      float4 m1 = msg4[(size_t)k * 50 + lane];
      v.x += m1.x; v.y += m1.y; v.z += m1.z; v.w += m1.w;
    }
    agg4[ap] = v;
  }
}

// ---------------- BatchNorm + gather ----------------
__global__ __launch_bounds__(256) void bn_reduce_kernel(const float* __restrict__ agg,
                                                        float* __restrict__ sums) {
  int tid = threadIdx.x;
  if (tid >= DIM) return;
  int row0 = blockIdx.x * 160;
  float s = 0.f, s2 = 0.f;
  for (int r = row0; r < row0 + 160; ++r) {
    float v = agg[(size_t)r * DIM + tid] * (1.f / 3.f);
    s += v; s2 += v * v;
  }
  atomicAdd(&sums[tid], s);
  atomicAdd(&sums[DIM + tid], s2);
}

__global__ __launch_bounds__(256) void bn_apply_kernel(const float* __restrict__ agg,
                                                       const float* __restrict__ sums,
                                                       MP gamma, MP beta,
                                                       void* __restrict__ xout, size_t ooff,
                                                       const int* __restrict__ flagp) {
  __shared__ float sc[DIM], sh[DIM];
  const int bf = *flagp;
  int tid = threadIdx.x;
  if (tid < DIM) {
    float mean = sums[tid] * (1.f / NENT);
    float var  = sums[DIM + tid] * (1.f / NENT) - mean * mean;
    float s = ld(gamma, tid, bf) * rsqrtf(var + EPSBN);
    sc[tid] = s;
    sh[tid] = ld(beta, tid, bf) - mean * s;
  }
  __syncthreads();
  int stride = gridDim.x * blockDim.x;
  for (int i = blockIdx.x * blockDim.x + tid; i < NENT * DIM; i += stride) {
    int c = i % DIM;
    float v = agg[i] * (1.f / 3.f);
    st(xout, ooff + i, tanhf(fmaf(v, sc[c], sh[c])), bf);
  }
}

__global__ void gather_kernel(void* __restrict__ out, const float* __restrict__ rfin,
                              const int* __restrict__ sub, const int* __restrict__ rel,
                              const int* __restrict__ flagp) {
  const int bf = *flagp;
  int i = blockIdx.x * 256 + threadIdx.x;
  MP xm; xm.p = out;
  if (i < BQ * DIM) {
    int b = i / DIM, c = i - b * DIM;
    st(out, i, ld(xm, XOFF + (size_t)sub[b] * DIM + c, bf), bf);
  } else if (i < 2 * BQ * DIM) {
    int j = i - BQ * DIM;
    int b = j / DIM, c = j - b * DIM;
    st(out, i, rfin[(size_t)rel[b] * DIM + c], bf);
  }
}

// ---------------- launch ----------------
extern "C" void kernel_launch(void* const* d_in, const int* in_sizes, int n_in,
                              void* d_out, int out_size, void* d_ws, size_t ws_size,
                              hipStream_t stream) {
  (void)in_sizes; (void)n_in; (void)out_size; (void)ws_size;
  const int* ei  = (const int*)d_in[0];
  const int* ety = (const int*)d_in[1];
  const int* qe  = (const int*)d_in[2];
  const int* qr  = (const int*)d_in[3];
  const int* sub = (const int*)d_in[4];
  const int* rel = (const int*)d_in[5];
  MP x0 = { d_in[6] };
  MP ir = { d_in[7] };
  MP w_loop[2] = { { d_in[8] },  { d_in[17] } };
  MP w_in[2]   = { { d_in[9] },  { d_in[18] } };
  MP w_out[2]  = { { d_in[10] }, { d_in[19] } };
  MP w_rel[2]  = { { d_in[11] }, { d_in[20] } };
  MP w_q[2]    = { { d_in[12] }, { d_in[21] } };
  MP lr[2]     = { { d_in[13] }, { d_in[22] } };
  MP gamma[2]  = { { d_in[15] }, { d_in[24] } };
  MP beta[2]   = { { d_in[16] }, { d_in[25] } };

  float* ws = (float*)d_ws;
  float* deg_in   = ws;                         // 40000
  float* deg_out  = ws + 40000;                 // 40000
  float* sums1    = ws + 80000;                 // 400
  float* sums2    = ws + 80400;                 // 400
  int*   flag     = (int*)(ws + 80800);         // 16
  float* normA    = ws + 80816;                 // 160000
  float* rel1     = ws + 240816;                // [200,200] f32
  float* rel2     = ws + 280816;
  float* rfin     = ws + 320816;
  unsigned short* bt = (unsigned short*)(ws + 440816);  // 8 x [208][224] bf16 -> ends 627184
  int*   cnt      = (int*)(ws + 627184);        // [2][40000]
  int*   offs     = (int*)(ws + 707184);        // [2][40001]
  int*   tmpo     = (int*)(ws + 787200);        // [2][40000]
  int*   perm     = (int*)(ws + 867200);        // [160000]
  float* msg      = ws + 1027200;               // [80000][200] f32, ends 17027200 < 18547184
  float* agg      = ws + 18547184;              // [40000][200] f32 (offset proven safe in r3)

  hipMemsetAsync(ws, 0, 80800 * sizeof(float), stream);       // deg + sums
  hipMemsetAsync(cnt, 0, 2 * NENT * sizeof(int), stream);     // dst counts

  detect_kernel<<<1, 64, 0, stream>>>((const unsigned short*)d_in[6], flag);
  deg_hist_kernel<<<(TOTE + 255) / 256, 256, 0, stream>>>(ei, deg_in, deg_out);
  norm_kernel<<<(TOTE + 255) / 256, 256, 0, stream>>>(ei, deg_in, deg_out, normA);
  cnt_kernel<<<(TOTE + 255) / 256, 256, 0, stream>>>(ei, cnt);
  scan_kernel<<<2, 256, 0, stream>>>(cnt, offs, tmpo);
  scatter_kernel<<<(TOTE + 255) / 256, 256, 0, stream>>>(ei, tmpo, perm);
  copy_f32_kernel<<<(DIM * DIM + 255) / 256, 256, 0, stream>>>(ir, rel1, DIM * DIM, flag);
  mat200_kernel<<<DIM, 256, 0, stream>>>(ir, 1, w_rel[0], rel2, flag);
  MP rel2m = { rel2 };
  mat200_kernel<<<DIM, 256, 0, stream>>>(rel2m, 0, w_rel[1], rfin, flag);

  // Bt: [0]=wq1 [1]=win1 [2]=wout1 [3]=wp1 [4]=wq2 [5]=win2 [6]=wout2 [7]=wp2
  MP nullmp = { nullptr };
  btprep_kernel<<<NP, 256, 0, stream>>>(w_q[0],   nullmp, 0, bt + 0ull * NP * KP, flag);
  btprep_kernel<<<NP, 256, 0, stream>>>(w_in[0],  nullmp, 0, bt + 1ull * NP * KP, flag);
  btprep_kernel<<<NP, 256, 0, stream>>>(w_out[0], nullmp, 0, bt + 2ull * NP * KP, flag);
  btprep_kernel<<<NP, 256, 0, stream>>>(w_loop[0], lr[0], 1, bt + 3ull * NP * KP, flag);
  btprep_kernel<<<NP, 256, 0, stream>>>(w_q[1],   nullmp, 0, bt + 4ull * NP * KP, flag);
  btprep_kernel<<<NP, 256, 0, stream>>>(w_in[1],  nullmp, 0, bt + 5ull * NP * KP, flag);
  btprep_kernel<<<NP, 256, 0, stream>>>(w_out[1], nullmp, 0, bt + 6ull * NP * KP, flag);
  btprep_kernel<<<NP, 256, 0, stream>>>(w_loop[1], lr[1], 1, bt + 7ull * NP * KP, flag);

  MP x1 = { d_out };

  // ---- layer 1 ----
  loop_mfma<<<MT_LOOP, 256, 0, stream>>>(x0, 0, bt + 3ull * NP * KP, agg, flag);
  edge_msg<<<MT_SIDE, 256, 0, stream>>>(x0, 0, rel1, ei, ety, qe, qr, normA, perm,
                                        bt + 0ull * NP * KP, bt + 1ull * NP * KP, msg, flag);
  segsum_kernel<<<NENT / 16, 256, 0, stream>>>((const float4*)msg, offs, (float4*)agg);
  edge_msg<<<MT_SIDE, 256, 0, stream>>>(x0, 0, rel1, ei, ety, qe, qr, normA, perm + EE,
                                        bt + 0ull * NP * KP, bt + 2ull * NP * KP, msg, flag);
  segsum_kernel<<<NENT / 16, 256, 0, stream>>>((const float4*)msg, offs + (NENT + 1), (float4*)agg);
  bn_reduce_kernel<<<NENT / 160, 256, 0, stream>>>(agg, sums1);
  bn_apply_kernel<<<2048, 256, 0, stream>>>(agg, sums1, gamma[0], beta[0], d_out, XOFF, flag);

  // ---- layer 2 (x1 lives in d_out x-region) ----
  loop_mfma<<<MT_LOOP, 256, 0, stream>>>(x1, XOFF, bt + 7ull * NP * KP, agg, flag);
  edge_msg<<<MT_SIDE, 256, 0, stream>>>(x1, XOFF, rel2, ei, ety, qe, qr, normA, perm,
                                        bt + 4ull * NP * KP, bt + 5ull * NP * KP, msg, flag);
  segsum_kernel<<<NENT / 16, 256, 0, stream>>>((const float4*)msg, offs, (float4*)agg);
  edge_msg<<<MT_SIDE, 256, 0, stream>>>(x1, XOFF, rel2, ei, ety, qe, qr, normA, perm + EE,
                                        bt + 4ull * NP * KP, bt + 6ull * NP * KP, msg, flag);
  segsum_kernel<<<NENT / 16, 256, 0, stream>>>((const float4*)msg, offs + (NENT + 1), (float4*)agg);
  bn_reduce_kernel<<<NENT / 160, 256, 0, stream>>>(agg, sums2);
  bn_apply_kernel<<<2048, 256, 0, stream>>>(agg, sums2, gamma[1], beta[1], d_out, XOFF, flag);

  gather_kernel<<<(2 * BQ * DIM + 255) / 256, 256, 0, stream>>>(d_out, rfin, sub, rel, flag);
}

// Round 3
// 936.869 us; speedup vs baseline: 1.0933x; 1.0933x over previous
//
#include <hip/hip_runtime.h>
#include <hip/hip_bf16.h>
#include <math.h>

using bf16 = __hip_bfloat16;

#define DEV static __device__ __forceinline__

constexpr int NENT = 40000;
constexpr int DIM  = 200;
constexpr int EE   = 80000;      // edges per side
constexpr int TOTE = 2 * EE;     // 160000
constexpr int BQ   = 1024;
constexpr float EPSBN = 1e-5f;
constexpr size_t XOFF = (size_t)2 * BQ * DIM;   // x-region element offset inside d_out

// MFMA geometry: N padded to 208 (13x16), K padded to 224 (7x32)
constexpr int KP   = 224;
constexpr int NP   = 208;
constexpr int LDAS = 232;        // LDS A stride (ushorts): 464B rows -> 2-way-max bank aliasing
constexpr int MT_LOOP = (NENT + 127) / 128;  // 313 (loop kernel M=128)
constexpr int MT_SIDE = EE / 64;             // 1250 per side; merged edge grid = 2500

typedef __attribute__((ext_vector_type(8))) short s8v;   // 8 x bf16 (4 VGPRs)
typedef __attribute__((ext_vector_type(4))) float f4v;   // MFMA accumulator
typedef __attribute__((ext_vector_type(4))) unsigned short us4;  // 4 x bf16 (8B)

struct MP { const void* p; };    // world-dtype (bf16|f32) pointer, runtime flag

DEV float b2f(unsigned int u) { union { unsigned int i; float f; } v; v.i = u << 16; return v.f; }

DEV float ld(MP m, size_t i, int bf) {
  return bf ? b2f(((const unsigned short*)m.p)[i]) : ((const float*)m.p)[i];
}
DEV void ld8(MP m, size_t i, float* o, int bf) {
  if (bf) {
    uint4 u = *(const uint4*)((const unsigned short*)m.p + i);
    o[0]=b2f(u.x & 0xffffu); o[1]=b2f(u.x >> 16);
    o[2]=b2f(u.y & 0xffffu); o[3]=b2f(u.y >> 16);
    o[4]=b2f(u.z & 0xffffu); o[5]=b2f(u.z >> 16);
    o[6]=b2f(u.w & 0xffffu); o[7]=b2f(u.w >> 16);
  } else {
    const float4* q = (const float4*)((const float*)m.p + i);
    float4 a = q[0], b = q[1];
    o[0]=a.x; o[1]=a.y; o[2]=a.z; o[3]=a.w; o[4]=b.x; o[5]=b.y; o[6]=b.z; o[7]=b.w;
  }
}
DEV void f32load8(const float* p, float* o) {
  const float4* q = (const float4*)p;
  float4 a = q[0], b = q[1];
  o[0]=a.x; o[1]=a.y; o[2]=a.z; o[3]=a.w; o[4]=b.x; o[5]=b.y; o[6]=b.z; o[7]=b.w;
}
DEV void st(void* p, size_t i, float v, int bf) {
  if (bf) ((bf16*)p)[i] = __float2bfloat16(v);
  else    ((float*)p)[i] = v;
}
DEV unsigned short f2b(float f) {   // RNE f32 -> bf16 bits (inputs never NaN)
  union { float f; unsigned int i; } v; v.f = f;
  return (unsigned short)((v.i + 0x7fffu + ((v.i >> 16) & 1u)) >> 16);
}
DEV uint4 pack8(const float* o) {
  uint4 u;
  u.x = (unsigned)f2b(o[0]) | ((unsigned)f2b(o[1]) << 16);
  u.y = (unsigned)f2b(o[2]) | ((unsigned)f2b(o[3]) << 16);
  u.z = (unsigned)f2b(o[4]) | ((unsigned)f2b(o[5]) << 16);
  u.w = (unsigned)f2b(o[6]) | ((unsigned)f2b(o[7]) << 16);
  return u;
}

// ---------------- dtype detect ----------------
__global__ void detect_kernel(const unsigned short* __restrict__ e, int* __restrict__ flag) {
  int tid = threadIdx.x;
  int absurd = 0;
  for (int i = tid; i < 2048; i += 64) {
    int ex = (e[i] >> 7) & 0xFF;
    if (ex >= 0xD0 || (ex != 0 && ex <= 0x50)) absurd++;
  }
  for (int o = 32; o; o >>= 1) absurd += __shfl_down(absurd, o);
  if (tid == 0) *flag = (absurd > 64) ? 0 : 1;   // 1 => bf16 world
}

// ---------------- small kernels ----------------
__global__ void deg_hist_kernel(const int* __restrict__ ei,
                                float* __restrict__ deg_in, float* __restrict__ deg_out) {
  int i = blockIdx.x * 256 + threadIdx.x;
  if (i >= TOTE) return;
  atomicAdd((i < EE ? deg_in : deg_out) + ei[i], 1.0f);
}

__global__ void norm_kernel(const int* __restrict__ ei,
                            const float* __restrict__ deg_in, const float* __restrict__ deg_out,
                            float* __restrict__ normA) {
  int i = blockIdx.x * 256 + threadIdx.x;
  if (i >= TOTE) return;
  int s = ei[i], d = ei[TOTE + i];
  const float* deg = (i < EE) ? deg_in : deg_out;
  float a = deg[s], b = deg[d];
  float na = a > 0.f ? rsqrtf(a) : 0.f;
  float nb = b > 0.f ? rsqrtf(b) : 0.f;
  normA[i] = na * nb;
}

// ---------------- dst-sort (counting sort per side) ----------------
__global__ void cnt_kernel(const int* __restrict__ ei, int* __restrict__ cnt) {
  int i = blockIdx.x * 256 + threadIdx.x;
  if (i >= TOTE) return;
  int side = (i >= EE) ? 1 : 0;
  atomicAdd(cnt + side * NENT + ei[TOTE + i], 1);
}

// 2 blocks (one per side), 256 threads: exclusive scan of cnt -> offs (+copy to tmpo)
__global__ __launch_bounds__(256) void scan_kernel(const int* __restrict__ cnt,
                                                   int* __restrict__ offs,
                                                   int* __restrict__ tmpo) {
  __shared__ int part[256];
  const int side = blockIdx.x;
  const int* c = cnt + side * NENT;
  int* o  = offs + side * (NENT + 1);
  int* tp = tmpo + side * NENT;
  const int t = threadIdx.x;
  const int CH = (NENT + 255) / 256;           // 157
  int lo = t * CH; if (lo > NENT) lo = NENT;
  int hi = lo + CH; if (hi > NENT) hi = NENT;
  int s = 0;
  for (int i = lo; i < hi; ++i) s += c[i];
  part[t] = s;
  __syncthreads();
  for (int d = 1; d < 256; d <<= 1) {
    int v = (t >= d) ? part[t - d] : 0;
    __syncthreads();
    part[t] += v;
    __syncthreads();
  }
  int run = (t == 0) ? 0 : part[t - 1];
  for (int i = lo; i < hi; ++i) { o[i] = run; tp[i] = run; run += c[i]; }
  if (t == 255) o[NENT] = run;                 // == EE
}

__global__ void scatter_kernel(const int* __restrict__ ei, int* __restrict__ tmpo,
                               int* __restrict__ perm) {
  int i = blockIdx.x * 256 + threadIdx.x;
  if (i >= TOTE) return;
  int side = (i >= EE) ? 1 : 0;
  int d = ei[TOTE + i];
  int p = atomicAdd(tmpo + side * NENT + d, 1);
  perm[side * EE + p] = i;
}

__global__ void copy_f32_kernel(MP s, float* __restrict__ d, int n, const int* __restrict__ flagp) {
  int bf = *flagp;
  int i = blockIdx.x * 256 + threadIdx.x;
  if (i < n) d[i] = ld(s, i, bf);
}

__global__ void mat200_kernel(MP A, int a_use_flag, MP B, float* __restrict__ C,
                              const int* __restrict__ flagp) {
  int bf = *flagp;
  int abf = a_use_flag ? bf : 0;
  int i = blockIdx.x, c = threadIdx.x;
  if (c >= DIM) return;
  float acc = 0.f;
  for (int d = 0; d < DIM; ++d)
    acc = fmaf(ld(A, (size_t)i * DIM + d, abf), ld(B, (size_t)d * DIM + c, bf), acc);
  C[(size_t)i * DIM + c] = acc;
}

// Bt[n][k] = W^T padded to [208][224] bf16, optionally folding loop_rel
__global__ void btprep_kernel(MP w, MP lrp, int has_lr, unsigned short* __restrict__ bt,
                              const int* __restrict__ flagp) {
  int bf = *flagp;
  int n = blockIdx.x, k = threadIdx.x;
  if (k >= KP) return;
  float v = 0.f;
  if (n < DIM && k < DIM) {
    v = ld(w, (size_t)k * DIM + n, bf);
    if (has_lr) v *= ld(lrp, k, bf);
  }
  bt[(size_t)n * KP + k] = f2b(v);
}

// ---------------- loop (self-edge) MFMA GEMM: agg = x @ wp'  (M=128, plain store) ----------------
__global__ __launch_bounds__(256, 2) void loop_mfma(
    MP x, size_t xoff, const unsigned short* __restrict__ Bt,
    float* __restrict__ agg, const int* __restrict__ flagp) {
  __shared__ unsigned short As[128][LDAS];
  const int bf  = *flagp;
  const int tid = threadIdx.x;
  const int m0  = blockIdx.x * 128;

  for (int i = tid; i < 128 * 28; i += 256) {
    int r = i / 28, cg = i - r * 28;
    float o[8] = {0,0,0,0,0,0,0,0};
    int row = m0 + r;
    if (row < NENT && cg < 25) ld8(x, xoff + (size_t)row * DIM + cg * 8, o, bf);
    *(uint4*)&As[r][cg * 8] = pack8(o);
  }
  __syncthreads();

  const int lane = tid & 63;
  const int w    = tid >> 6;
  const int col  = lane & 15;
  const int quad = lane >> 4;
  const unsigned short* btl = Bt + (size_t)col * KP + quad * 8;

  f4v acc[26];
#pragma unroll
  for (int t = 0; t < 26; ++t) acc[t] = (f4v){0.f, 0.f, 0.f, 0.f};

  const int rbase = w * 32;
#pragma unroll
  for (int kc = 0; kc < 7; ++kc) {
    const int k0 = kc * 32;
    s8v a0 = __builtin_bit_cast(s8v, *(const uint4*)&As[rbase + col][k0 + quad * 8]);
    s8v a1 = __builtin_bit_cast(s8v, *(const uint4*)&As[rbase + 16 + col][k0 + quad * 8]);
#pragma unroll
    for (int nt = 0; nt < 13; ++nt) {
      s8v b = __builtin_bit_cast(s8v, *(const uint4*)(btl + (size_t)nt * 16 * KP + k0));
      acc[nt]      = __builtin_amdgcn_mfma_f32_16x16x32_bf16(a0, b, acc[nt], 0, 0, 0);
      acc[13 + nt] = __builtin_amdgcn_mfma_f32_16x16x32_bf16(a1, b, acc[13 + nt], 0, 0, 0);
    }
  }

#pragma unroll
  for (int mt = 0; mt < 2; ++mt) {
#pragma unroll
    for (int i = 0; i < 4; ++i) {
      const int grow = m0 + rbase + mt * 16 + quad * 4 + i;
      if (grow < NENT) {
        float* ap = agg + (size_t)grow * DIM;
#pragma unroll
        for (int nt = 0; nt < 13; ++nt) {
          int n = nt * 16 + col;
          if (n < DIM) ap[n] = acc[mt * 13 + nt][i];
        }
      }
    }
  }
}

// ---------------- phase A (merged sides): qual GEMM -> rel_e -> m (LDS C->A) -> msg GEMM ----
// grid = 2*MT_SIDE: blocks [0,1250) process the in-side, [1250,2500) the out-side.
// Rows come in dst-sorted order via perm; result msg*norm stored as bf16 (coalesced, no atomics)
// at sorted position so phase B does a fully-contiguous segmented sum for both sides at once.
// M=64 tile, 1 m-tile/wave: each wave reads/rewrites ONLY As rows [16w,16w+16) after staging,
// so the C->A transpose through LDS needs no extra barriers (wave-private rows).
__global__ __launch_bounds__(256, 5) void edge_msg(
    MP x, size_t xoff, const float* __restrict__ re,
    const int* __restrict__ ei, const int* __restrict__ ety,
    const int* __restrict__ qe, const int* __restrict__ qr,
    const float* __restrict__ normA, const int* __restrict__ perm,
    const unsigned short* __restrict__ BtQ,
    const unsigned short* __restrict__ BtIn, const unsigned short* __restrict__ BtOut,
    unsigned short* __restrict__ msg, const int* __restrict__ flagp) {
  __shared__ unsigned short As[64][LDAS];           // 29.7 KB
  __shared__ int sQe0[64], sQe1[64], sQr0[64], sQr1[64], sSrc[64], sEty[64];
  __shared__ float sN[64];

  const int bf  = *flagp;
  const int tid = threadIdx.x;
  const int bid  = blockIdx.x;
  const int side = (bid >= MT_SIDE) ? 1 : 0;
  const int m0   = (bid - side * MT_SIDE) * 64;     // position within this side's sorted order
  const int* permS = perm + side * EE;
  const unsigned short* BtW = side ? BtOut : BtIn;
  const size_t mrow0 = (size_t)side * EE + m0;      // msg row base (side-major layout)

  if (tid < 64) {
    int e = permS[m0 + tid];                        // original edge id
    sQe0[tid] = qe[e];        sQe1[tid] = qe[TOTE + e];
    sQr0[tid] = qr[e];        sQr1[tid] = qr[TOTE + e];
    sSrc[tid] = ei[e];        sEty[tid] = ety[e];
    sN[tid]   = normA[e];
  }
  __syncthreads();

  // stage t1 = sum_q x[qe]*re[qr] into As (64 x 224 bf16), pad cols zeroed
  for (int i = tid; i < 64 * 28; i += 256) {
    int r = i / 28, cg = i - r * 28;
    float o[8] = {0,0,0,0,0,0,0,0};
    if (cg < 25) {
      float xa[8], ra[8], xb[8], rb[8];
      ld8(x, xoff + (size_t)sQe0[r] * DIM + cg * 8, xa, bf);
      f32load8(re + (size_t)sQr0[r] * DIM + cg * 8, ra);
      ld8(x, xoff + (size_t)sQe1[r] * DIM + cg * 8, xb, bf);
      f32load8(re + (size_t)sQr1[r] * DIM + cg * 8, rb);
#pragma unroll
      for (int j = 0; j < 8; ++j) o[j] = xa[j] * ra[j] + xb[j] * rb[j];
    }
    *(uint4*)&As[r][cg * 8] = pack8(o);
  }
  __syncthreads();
  // ---- from here on, wave w touches only As rows [16w, 16w+16) ----

  const int lane = tid & 63;
  const int w    = tid >> 6;
  const int col  = lane & 15;
  const int quad = lane >> 4;
  const int rbase = w * 16;

  f4v acc[13];
#pragma unroll
  for (int t = 0; t < 13; ++t) acc[t] = (f4v){0.f, 0.f, 0.f, 0.f};

  // GEMM 1: qual = t1 @ w_q^T
  {
    const unsigned short* btl = BtQ + (size_t)col * KP + quad * 8;
#pragma unroll
    for (int kc = 0; kc < 7; ++kc) {
      const int k0 = kc * 32;
      s8v a = __builtin_bit_cast(s8v, *(const uint4*)&As[rbase + col][k0 + quad * 8]);
#pragma unroll
      for (int nt = 0; nt < 13; ++nt) {
        s8v b = __builtin_bit_cast(s8v, *(const uint4*)(btl + (size_t)nt * 16 * KP + k0));
        acc[nt] = __builtin_amdgcn_mfma_f32_16x16x32_bf16(a, b, acc[nt], 0, 0, 0);
      }
    }
  }

  // epilogue 1: m = x[src] * 0.5*(re[ety] + qual) -> back into own As rows (C->A transpose)
#pragma unroll
  for (int i = 0; i < 4; ++i) {
    const int lrow = rbase + quad * 4 + i;
    const float* rerow = re + (size_t)sEty[lrow] * DIM;
    const size_t xrow = xoff + (size_t)sSrc[lrow] * DIM;
#pragma unroll
    for (int nt = 0; nt < 13; ++nt) {
      int n = nt * 16 + col;
      float v = 0.f;
      if (n < DIM) v = ld(x, xrow + n, bf) * (0.5f * (rerow[n] + acc[nt][i]));
      if (n < NP) As[lrow][n] = f2b(v);
    }
    As[lrow][NP + col] = 0;    // zero k-pad cols 208..223
  }

#pragma unroll
  for (int t = 0; t < 13; ++t) acc[t] = (f4v){0.f, 0.f, 0.f, 0.f};

  // GEMM 2: msg = m @ (w_in|w_out)^T   (same wave-private As rows; lgkmcnt orders write->read)
  {
    const unsigned short* btl = BtW + (size_t)col * KP + quad * 8;
#pragma unroll
    for (int kc = 0; kc < 7; ++kc) {
      const int k0 = kc * 32;
      s8v a = __builtin_bit_cast(s8v, *(const uint4*)&As[rbase + col][k0 + quad * 8]);
#pragma unroll
      for (int nt = 0; nt < 13; ++nt) {
        s8v b = __builtin_bit_cast(s8v, *(const uint4*)(btl + (size_t)nt * 16 * KP + k0));
        acc[nt] = __builtin_amdgcn_mfma_f32_16x16x32_bf16(a, b, acc[nt], 0, 0, 0);
      }
    }
  }

  // epilogue 2: msg[sorted_pos] = bf16(acc * norm)  (plain coalesced stores, no atomics)
#pragma unroll
  for (int i = 0; i < 4; ++i) {
    const int lrow = rbase + quad * 4 + i;
    const float nv = sN[lrow];
    unsigned short* mp = msg + (mrow0 + lrow) * DIM;
#pragma unroll
    for (int nt = 0; nt < 13; ++nt) {
      int n = nt * 16 + col;
      if (n < DIM) mp[n] = f2b(acc[nt][i] * nv);
    }
  }
}

// ---------------- phase B: combined contiguous segmented sum over BOTH sides ----
// agg[d] += sum(msgIn[offsI[d]:offsI[d+1]]) + sum(msgOut[offsO[d]:offsO[d+1]])
// msg rows for entity d are contiguous (dst-sorted) -> fully streaming 8B bf16 reads;
// agg touched exactly once per layer.
__global__ __launch_bounds__(256) void segsum_kernel(const unsigned short* __restrict__ msg,
                                                     const int* __restrict__ offsI,
                                                     const int* __restrict__ offsO,
                                                     float4* __restrict__ agg4) {
  const int lane = threadIdx.x & 63;
  const int w    = threadIdx.x >> 6;
  if (lane >= 50) return;                 // 50 x (4 cols) = 200 cols
  const int rbase = blockIdx.x * 16 + w * 4;
#pragma unroll
  for (int rr = 0; rr < 4; ++rr) {
    const int d = rbase + rr;
    const size_t ap = (size_t)d * 50 + lane;
    float4 v = agg4[ap];
    int b = offsI[d], e = offsI[d + 1];
    for (int k = b; k < e; ++k) {
      us4 u = *(const us4*)(msg + (size_t)k * DIM + lane * 4);
      v.x += b2f(u[0]); v.y += b2f(u[1]); v.z += b2f(u[2]); v.w += b2f(u[3]);
    }
    b = offsO[d]; e = offsO[d + 1];
    for (int k = b; k < e; ++k) {
      us4 u = *(const us4*)(msg + (size_t)(EE + k) * DIM + lane * 4);
      v.x += b2f(u[0]); v.y += b2f(u[1]); v.z += b2f(u[2]); v.w += b2f(u[3]);
    }
    agg4[ap] = v;
  }
}

// ---------------- BatchNorm + gather ----------------
__global__ __launch_bounds__(256) void bn_reduce_kernel(const float* __restrict__ agg,
                                                        float* __restrict__ sums) {
  int tid = threadIdx.x;
  if (tid >= DIM) return;
  int row0 = blockIdx.x * 160;
  float s = 0.f, s2 = 0.f;
  for (int r = row0; r < row0 + 160; ++r) {
    float v = agg[(size_t)r * DIM + tid] * (1.f / 3.f);
    s += v; s2 += v * v;
  }
  atomicAdd(&sums[tid], s);
  atomicAdd(&sums[DIM + tid], s2);
}

__global__ __launch_bounds__(256) void bn_apply_kernel(const float* __restrict__ agg,
                                                       const float* __restrict__ sums,
                                                       MP gamma, MP beta,
                                                       void* __restrict__ xout, size_t ooff,
                                                       const int* __restrict__ flagp) {
  __shared__ float sc[DIM], sh[DIM];
  const int bf = *flagp;
  int tid = threadIdx.x;
  if (tid < DIM) {
    float mean = sums[tid] * (1.f / NENT);
    float var  = sums[DIM + tid] * (1.f / NENT) - mean * mean;
    float s = ld(gamma, tid, bf) * rsqrtf(var + EPSBN);
    sc[tid] = s;
    sh[tid] = ld(beta, tid, bf) - mean * s;
  }
  __syncthreads();
  int stride = gridDim.x * blockDim.x;
  for (int i = blockIdx.x * blockDim.x + tid; i < NENT * DIM; i += stride) {
    int c = i % DIM;
    float v = agg[i] * (1.f / 3.f);
    st(xout, ooff + i, tanhf(fmaf(v, sc[c], sh[c])), bf);
  }
}

__global__ void gather_kernel(void* __restrict__ out, const float* __restrict__ rfin,
                              const int* __restrict__ sub, const int* __restrict__ rel,
                              const int* __restrict__ flagp) {
  const int bf = *flagp;
  int i = blockIdx.x * 256 + threadIdx.x;
  MP xm; xm.p = out;
  if (i < BQ * DIM) {
    int b = i / DIM, c = i - b * DIM;
    st(out, i, ld(xm, XOFF + (size_t)sub[b] * DIM + c, bf), bf);
  } else if (i < 2 * BQ * DIM) {
    int j = i - BQ * DIM;
    int b = j / DIM, c = j - b * DIM;
    st(out, i, rfin[(size_t)rel[b] * DIM + c], bf);
  }
}

// ---------------- launch ----------------
extern "C" void kernel_launch(void* const* d_in, const int* in_sizes, int n_in,
                              void* d_out, int out_size, void* d_ws, size_t ws_size,
                              hipStream_t stream) {
  (void)in_sizes; (void)n_in; (void)out_size; (void)ws_size;
  const int* ei  = (const int*)d_in[0];
  const int* ety = (const int*)d_in[1];
  const int* qe  = (const int*)d_in[2];
  const int* qr  = (const int*)d_in[3];
  const int* sub = (const int*)d_in[4];
  const int* rel = (const int*)d_in[5];
  MP x0 = { d_in[6] };
  MP ir = { d_in[7] };
  MP w_loop[2] = { { d_in[8] },  { d_in[17] } };
  MP w_in[2]   = { { d_in[9] },  { d_in[18] } };
  MP w_out[2]  = { { d_in[10] }, { d_in[19] } };
  MP w_rel[2]  = { { d_in[11] }, { d_in[20] } };
  MP w_q[2]    = { { d_in[12] }, { d_in[21] } };
  MP lr[2]     = { { d_in[13] }, { d_in[22] } };
  MP gamma[2]  = { { d_in[15] }, { d_in[24] } };
  MP beta[2]   = { { d_in[16] }, { d_in[25] } };

  float* ws = (float*)d_ws;
  float* deg_in   = ws;                         // 40000
  float* deg_out  = ws + 40000;                 // 40000
  float* sums1    = ws + 80000;                 // 400
  float* sums2    = ws + 80400;                 // 400
  int*   flag     = (int*)(ws + 80800);         // 16
  float* normA    = ws + 80816;                 // 160000
  float* rel1     = ws + 240816;                // [200,200] f32
  float* rel2     = ws + 280816;
  float* rfin     = ws + 320816;
  unsigned short* bt = (unsigned short*)(ws + 440816);  // 8 x [208][224] bf16 -> ends 627184
  int*   cnt      = (int*)(ws + 627184);        // [2][40000]
  int*   offs     = (int*)(ws + 707184);        // [2][40001]
  int*   tmpo     = (int*)(ws + 787200);        // [2][40000]
  int*   perm     = (int*)(ws + 867200);        // [160000]
  unsigned short* msg = (unsigned short*)(ws + 1027200); // [160000][200] bf16 = 16M floats, ends 17027200 < 18547184
  float* agg      = ws + 18547184;              // [40000][200] f32 (offset proven safe in r3)

  hipMemsetAsync(ws, 0, 80800 * sizeof(float), stream);       // deg + sums
  hipMemsetAsync(cnt, 0, 2 * NENT * sizeof(int), stream);     // dst counts

  detect_kernel<<<1, 64, 0, stream>>>((const unsigned short*)d_in[6], flag);
  deg_hist_kernel<<<(TOTE + 255) / 256, 256, 0, stream>>>(ei, deg_in, deg_out);
  norm_kernel<<<(TOTE + 255) / 256, 256, 0, stream>>>(ei, deg_in, deg_out, normA);
  cnt_kernel<<<(TOTE + 255) / 256, 256, 0, stream>>>(ei, cnt);
  scan_kernel<<<2, 256, 0, stream>>>(cnt, offs, tmpo);
  scatter_kernel<<<(TOTE + 255) / 256, 256, 0, stream>>>(ei, tmpo, perm);
  copy_f32_kernel<<<(DIM * DIM + 255) / 256, 256, 0, stream>>>(ir, rel1, DIM * DIM, flag);
  mat200_kernel<<<DIM, 256, 0, stream>>>(ir, 1, w_rel[0], rel2, flag);
  MP rel2m = { rel2 };
  mat200_kernel<<<DIM, 256, 0, stream>>>(rel2m, 0, w_rel[1], rfin, flag);

  // Bt: [0]=wq1 [1]=win1 [2]=wout1 [3]=wp1 [4]=wq2 [5]=win2 [6]=wout2 [7]=wp2
  MP nullmp = { nullptr };
  btprep_kernel<<<NP, 256, 0, stream>>>(w_q[0],   nullmp, 0, bt + 0ull * NP * KP, flag);
  btprep_kernel<<<NP, 256, 0, stream>>>(w_in[0],  nullmp, 0, bt + 1ull * NP * KP, flag);
  btprep_kernel<<<NP, 256, 0, stream>>>(w_out[0], nullmp, 0, bt + 2ull * NP * KP, flag);
  btprep_kernel<<<NP, 256, 0, stream>>>(w_loop[0], lr[0], 1, bt + 3ull * NP * KP, flag);
  btprep_kernel<<<NP, 256, 0, stream>>>(w_q[1],   nullmp, 0, bt + 4ull * NP * KP, flag);
  btprep_kernel<<<NP, 256, 0, stream>>>(w_in[1],  nullmp, 0, bt + 5ull * NP * KP, flag);
  btprep_kernel<<<NP, 256, 0, stream>>>(w_out[1], nullmp, 0, bt + 6ull * NP * KP, flag);
  btprep_kernel<<<NP, 256, 0, stream>>>(w_loop[1], lr[1], 1, bt + 7ull * NP * KP, flag);

  MP x1 = { d_out };

  // ---- layer 1 ----
  loop_mfma<<<MT_LOOP, 256, 0, stream>>>(x0, 0, bt + 3ull * NP * KP, agg, flag);
  edge_msg<<<2 * MT_SIDE, 256, 0, stream>>>(x0, 0, rel1, ei, ety, qe, qr, normA, perm,
                                            bt + 0ull * NP * KP, bt + 1ull * NP * KP,
                                            bt + 2ull * NP * KP, msg, flag);
  segsum_kernel<<<NENT / 16, 256, 0, stream>>>(msg, offs, offs + (NENT + 1), (float4*)agg);
  bn_reduce_kernel<<<NENT / 160, 256, 0, stream>>>(agg, sums1);
  bn_apply_kernel<<<2048, 256, 0, stream>>>(agg, sums1, gamma[0], beta[0], d_out, XOFF, flag);

  // ---- layer 2 (x1 lives in d_out x-region) ----
  loop_mfma<<<MT_LOOP, 256, 0, stream>>>(x1, XOFF, bt + 7ull * NP * KP, agg, flag);
  edge_msg<<<2 * MT_SIDE, 256, 0, stream>>>(x1, XOFF, rel2, ei, ety, qe, qr, normA, perm,
                                            bt + 4ull * NP * KP, bt + 5ull * NP * KP,
                                            bt + 6ull * NP * KP, msg, flag);
  segsum_kernel<<<NENT / 16, 256, 0, stream>>>(msg, offs, offs + (NENT + 1), (float4*)agg);
  bn_reduce_kernel<<<NENT / 160, 256, 0, stream>>>(agg, sums2);
  bn_apply_kernel<<<2048, 256, 0, stream>>>(agg, sums2, gamma[1], beta[1], d_out, XOFF, flag);

  gather_kernel<<<(2 * BQ * DIM + 255) / 256, 256, 0, stream>>>(d_out, rfin, sub, rel, flag);
}